// Round 5
// baseline (6202.494 us; speedup 1.0000x reference)
//
#include <hip/hip_runtime.h>

#define D   128
#define OD  384   // 3*D output row stride
#define NK  25    // KS^2 kernels

typedef __attribute__((ext_vector_type(8))) short bf16x8;
typedef __attribute__((ext_vector_type(4))) float f32x4;
typedef __attribute__((ext_vector_type(4))) unsigned int u32x4;

__device__ inline unsigned short f2bf(float f) {
  unsigned int u = __float_as_uint(f);
  u += 0x7fffu + ((u >> 16) & 1u);
  return (unsigned short)(u >> 16);
}

// swizzled flat index for G[r][ch], G = float[128*128]; XOR 16B-chunk swizzle
__device__ inline int gaddr(int r, int ch) {
  return r * 128 + ((((ch >> 2) ^ (r & 7)) << 2) | (ch & 3));
}

// ---------------- preprocessing: corner counting sort by (dst-block, k) ------

__global__ __launch_bounds__(256) void count_kernel(const int* __restrict__ dstA,
    const float* __restrict__ attr, int E, int* __restrict__ deg,
    int* __restrict__ cnt) {
  int e = blockIdx.x * 256 + threadIdx.x;
  if (e >= E) return;
  int d = dstA[e];
  atomicAdd(&deg[d], 1);
  float v0 = attr[2 * e] * 4.0f;
  float v1 = attr[2 * e + 1] * 4.0f;
  int i0 = min(3, max(0, (int)v0));
  int i1 = min(3, max(0, (int)v1));
  int b = (d >> 7) * NK + i0 + 5 * i1;
  atomicAdd(&cnt[b], 1);
  atomicAdd(&cnt[b + 1], 1);
  atomicAdd(&cnt[b + 5], 1);
  atomicAdd(&cnt[b + 6], 1);
}

// exclusive scan over cnt[M] -> boffs[M+1], cursor[M]; single block
__global__ __launch_bounds__(1024) void scan_kernel(const int* __restrict__ cnt, int M,
    int* __restrict__ boffs, int* __restrict__ cursor) {
  __shared__ int part[1024];
  int tid = threadIdx.x;
  int chunk = (M + 1023) / 1024;
  int s0 = min(M, tid * chunk), s1 = min(M, s0 + chunk);
  int sum = 0;
  for (int i = s0; i < s1; ++i) sum += cnt[i];
  part[tid] = sum;
  __syncthreads();
  if (tid == 0) {
    int acc = 0;
    for (int i = 0; i < 1024; ++i) { int t = part[i]; part[i] = acc; acc += t; }
  }
  __syncthreads();
  int acc = part[tid];
  for (int i = s0; i < s1; ++i) { boffs[i] = acc; cursor[i] = acc; acc += cnt[i]; }
  if (tid == 1023) boffs[M] = acc;
}

__global__ __launch_bounds__(256) void fill_kernel(const int* __restrict__ srcA,
    const int* __restrict__ dstA, const float* __restrict__ attr, int E,
    int* __restrict__ cursor, unsigned int* __restrict__ rMeta,
    _Float16* __restrict__ rB) {
  int e = blockIdx.x * 256 + threadIdx.x;
  if (e >= E) return;
  int s = srcA[e], d = dstA[e];
  float v0 = attr[2 * e] * 4.0f;
  float v1 = attr[2 * e + 1] * 4.0f;
  int i0 = min(3, max(0, (int)v0));
  int i1 = min(3, max(0, (int)v1));
  float f0 = v0 - (float)i0;
  float f1 = v1 - (float)i1;
  unsigned int meta = (unsigned int)s | ((unsigned int)(d & 127) << 17);
  int bb = (d >> 7) * NK + i0 + 5 * i1;
  int p;
  p = atomicAdd(&cursor[bb], 1);     rMeta[p] = meta; rB[p] = (_Float16)((1.f - f0) * (1.f - f1));
  p = atomicAdd(&cursor[bb + 1], 1); rMeta[p] = meta; rB[p] = (_Float16)(f0 * (1.f - f1));
  p = atomicAdd(&cursor[bb + 5], 1); rMeta[p] = meta; rB[p] = (_Float16)((1.f - f0) * f1);
  p = atomicAdd(&cursor[bb + 6], 1); rMeta[p] = meta; rB[p] = (_Float16)(f0 * f1);
}

// WTf fragment-major bf16: frag (k,ks,nc), lane l, elem j -> W[k][i][o],
// i = ks*32 + (l>>4)*8 + j, o = nc*16 + (l&15). 16B per lane, coalesced.
__global__ __launch_bounds__(256) void wtf_kernel(const float* __restrict__ W,
                                                  unsigned short* __restrict__ WTf) {
  int idx = blockIdx.x * 256 + threadIdx.x;
  if (idx >= NK * 4 * 8 * 512) return;
  int j  = idx & 7;
  int l  = (idx >> 3) & 63;
  int nc = (idx >> 9) & 7;
  int ks = (idx >> 12) & 3;
  int k  = idx >> 14;
  int i = ks * 32 + (l >> 4) * 8 + j;
  int o = nc * 16 + (l & 15);
  WTf[idx] = f2bf(W[((size_t)k * 128 + i) * 128 + o]);
}

// ---------------- fused gather+MFMA: Y[blk rows] = sum_k G_k @ W[k] ----------
// 512 threads (8 waves) per block; block owns 128 dst rows; G lives in LDS only.

__global__ __launch_bounds__(512) void fused_kernel(const int* __restrict__ boffs,
    const unsigned int* __restrict__ rMeta, const _Float16* __restrict__ rB,
    const unsigned short* __restrict__ Xb, const unsigned short* __restrict__ WTf,
    float* __restrict__ Y, int N) {
  __shared__ float G[128 * 128];
  const int tid = threadIdx.x;
  const int wv = tid >> 6, l = tid & 63;
  const int blk = blockIdx.x;
  f32x4 acc[8];
#pragma unroll
  for (int nc = 0; nc < 8; ++nc) acc[nc] = (f32x4){0.f, 0.f, 0.f, 0.f};

  const int a_r = wv * 16 + (l & 15);  // A-row this lane reads for MFMA
  const int ch0 = (l >> 4) * 8;        // A-col base within 32-elem k-block

  for (int k = 0; k < NK; ++k) {
    for (int t = tid; t < 128 * 128; t += 512) G[t] = 0.f;
    __syncthreads();
    int o0 = boffs[blk * NK + k], o1 = boffs[blk * NK + k + 1];
    int len = o1 - o0;
    int j = o0 + ((len * wv) >> 3);
    int je = o0 + ((len * (wv + 1)) >> 3);
    for (; j + 3 < je; j += 4) {
      unsigned int mt[4]; float bw[4]; unsigned int xp[4];
#pragma unroll
      for (int u = 0; u < 4; ++u) mt[u] = rMeta[j + u];
#pragma unroll
      for (int u = 0; u < 4; ++u) bw[u] = (float)rB[j + u];
#pragma unroll
      for (int u = 0; u < 4; ++u)
        xp[u] = *(const unsigned int*)(Xb + (size_t)(mt[u] & 0x1FFFFu) * D + l * 2);
#pragma unroll
      for (int u = 0; u < 4; ++u) {
        int d7 = (int)(mt[u] >> 17);
        float x0 = __uint_as_float(xp[u] << 16);
        float x1 = __uint_as_float(xp[u] & 0xffff0000u);
        int a0 = gaddr(d7, 2 * l);
        atomicAdd(&G[a0], bw[u] * x0);
        atomicAdd(&G[a0 + 1], bw[u] * x1);
      }
    }
    for (; j < je; ++j) {
      unsigned int mtu = rMeta[j];
      float bwu = (float)rB[j];
      unsigned int xpu = *(const unsigned int*)(Xb + (size_t)(mtu & 0x1FFFFu) * D + l * 2);
      int d7 = (int)(mtu >> 17);
      float x0 = __uint_as_float(xpu << 16);
      float x1 = __uint_as_float(xpu & 0xffff0000u);
      int a0 = gaddr(d7, 2 * l);
      atomicAdd(&G[a0], bwu * x0);
      atomicAdd(&G[a0 + 1], bwu * x1);
    }
    __syncthreads();
    const unsigned short* Wk = WTf + (size_t)k * (4 * 8 * 512);
#pragma unroll
    for (int ks = 0; ks < 4; ++ks) {
      int c0 = ks * 32 + ch0;
      float4 fa = *(const float4*)&G[gaddr(a_r, c0)];
      float4 fb = *(const float4*)&G[gaddr(a_r, c0 + 4)];
      u32x4 pk;
      pk[0] = (unsigned int)f2bf(fa.x) | ((unsigned int)f2bf(fa.y) << 16);
      pk[1] = (unsigned int)f2bf(fa.z) | ((unsigned int)f2bf(fa.w) << 16);
      pk[2] = (unsigned int)f2bf(fb.x) | ((unsigned int)f2bf(fb.y) << 16);
      pk[3] = (unsigned int)f2bf(fb.z) | ((unsigned int)f2bf(fb.w) << 16);
      bf16x8 av = __builtin_bit_cast(bf16x8, pk);
      const unsigned short* wrow = Wk + (size_t)ks * (8 * 512) + l * 8;
#pragma unroll
      for (int nc = 0; nc < 8; ++nc) {
        bf16x8 bv = *(const bf16x8*)(wrow + (size_t)nc * 512);
        acc[nc] = __builtin_amdgcn_mfma_f32_16x16x32_bf16(av, bv, acc[nc], 0, 0, 0);
      }
    }
    __syncthreads();
  }
  const int m0 = blk * 128;
#pragma unroll
  for (int nc = 0; nc < 8; ++nc) {
    int col = nc * 16 + (l & 15);
#pragma unroll
    for (int jj = 0; jj < 4; ++jj) {
      int row = m0 + wv * 16 + (l >> 4) * 4 + jj;
      if (row < N) Y[(size_t)row * D + col] = acc[nc][jj];
    }
  }
}

// ---------------- per-row l2norm / finalize ----------------------------------

__global__ __launch_bounds__(256) void l2norm_x_kernel(const float* __restrict__ x,
    float* __restrict__ out, unsigned short* __restrict__ xbf, int N) {
  int g = blockIdx.x * 256 + threadIdx.x;
  int n = g >> 6, lane = g & 63;
  if (n >= N) return;
  float2 v = *(const float2*)(x + (size_t)n * D + lane * 2);
  float ss = v.x * v.x + v.y * v.y;
#pragma unroll
  for (int m = 1; m < 64; m <<= 1) ss += __shfl_xor(ss, m, 64);
  float r = 1.0f / fmaxf(sqrtf(ss), 1e-12f);
  *(float2*)(out + (size_t)n * OD + lane * 2) = make_float2(v.x * r, v.y * r);
  unsigned int pk = (unsigned int)f2bf(v.x) | ((unsigned int)f2bf(v.y) << 16);
  *(unsigned int*)(xbf + (size_t)n * D + lane * 2) = pk;
}

__global__ __launch_bounds__(256) void finalize_kernel(const float* __restrict__ y,
    const int* __restrict__ deg, const float* __restrict__ bias, float* __restrict__ out,
    unsigned short* __restrict__ xnext, int N) {
  int g = blockIdx.x * 256 + threadIdx.x;
  int n = g >> 6, lane = g & 63;
  if (n >= N) return;
  float inv = 1.0f / (float)max(deg[n], 1);
  float2 a = *(const float2*)(y + (size_t)n * D + lane * 2);
  float2 b = *(const float2*)(bias + lane * 2);
  float h0 = a.x * inv + b.x;
  float h1 = a.y * inv + b.y;
  float ss = h0 * h0 + h1 * h1;
#pragma unroll
  for (int m = 1; m < 64; m <<= 1) ss += __shfl_xor(ss, m, 64);
  float r = 1.0f / fmaxf(sqrtf(ss), 1e-12f);
  *(float2*)(out + (size_t)n * OD + lane * 2) = make_float2(h0 * r, h1 * r);
  if (xnext) {
    unsigned int pk = (unsigned int)f2bf(fmaxf(h0, 0.f)) |
                      ((unsigned int)f2bf(fmaxf(h1, 0.f)) << 16);
    *(unsigned int*)(xnext + (size_t)n * D + lane * 2) = pk;
  }
}

// ---------------- launch ------------------------------------------------------

extern "C" void kernel_launch(void* const* d_in, const int* in_sizes, int n_in,
                              void* d_out, int out_size, void* d_ws, size_t ws_size,
                              hipStream_t stream) {
  const float* x    = (const float*)d_in[0];
  const int*   ei   = (const int*)d_in[1];
  const float* attr = (const float*)d_in[2];
  const float* w0   = (const float*)d_in[3];
  const float* b0   = (const float*)d_in[4];
  const float* w1   = (const float*)d_in[5];
  const float* b1   = (const float*)d_in[6];
  float* out = (float*)d_out;

  const int N = in_sizes[0] / D;
  const int E = in_sizes[1] / 2;
  const int* srcA = ei;
  const int* dstA = ei + E;
  const int NBLK = (N + 127) / 128;
  const int NBUCK = NBLK * NK;

  char* p = (char*)d_ws;
  auto carve = [&](size_t bytes) -> char* {
    char* r = p;
    p += (bytes + 255) & ~(size_t)255;
    return r;
  };
  unsigned short* xbf    = (unsigned short*)carve((size_t)N * D * 2);
  unsigned short* xtmp   = (unsigned short*)carve((size_t)N * D * 2);
  float*          ygemm  = (float*)carve((size_t)N * D * 4);
  int*            deg    = (int*)carve((size_t)N * 4);
  int*            cnt    = (int*)carve((size_t)NBUCK * 4);
  int*            boffs  = (int*)carve((size_t)(NBUCK + 1) * 4);
  int*            cursor = (int*)carve((size_t)NBUCK * 4);
  unsigned int*   rMeta  = (unsigned int*)carve((size_t)E * 4 * 4);
  _Float16*       rB     = (_Float16*)carve((size_t)E * 4 * 2);
  unsigned short* WTf0   = (unsigned short*)carve((size_t)NK * 4 * 8 * 512 * 2);
  unsigned short* WTf1   = (unsigned short*)carve((size_t)NK * 4 * 8 * 512 * 2);
  (void)n_in; (void)out_size; (void)ws_size;

  hipMemsetAsync(deg, 0, (size_t)N * 4, stream);
  hipMemsetAsync(cnt, 0, (size_t)NBUCK * 4, stream);

  int eb = (E + 255) / 256;
  count_kernel<<<eb, 256, 0, stream>>>(dstA, attr, E, deg, cnt);
  scan_kernel<<<1, 1024, 0, stream>>>(cnt, NBUCK, boffs, cursor);
  fill_kernel<<<eb, 256, 0, stream>>>(srcA, dstA, attr, E, cursor, rMeta, rB);
  int wtb = (NK * 4 * 8 * 512 + 255) / 256;
  wtf_kernel<<<wtb, 256, 0, stream>>>(w0, WTf0);
  wtf_kernel<<<wtb, 256, 0, stream>>>(w1, WTf1);

  int nb = (N * 64 + 255) / 256;
  l2norm_x_kernel<<<nb, 256, 0, stream>>>(x, out, xbf, N);

  const float* Bv[2] = {b0, b1};
  const unsigned short* WTl[2] = {WTf0, WTf1};
  const unsigned short* xin = xbf;
  for (int layer = 0; layer < 2; ++layer) {
    fused_kernel<<<NBLK, 512, 0, stream>>>(boffs, rMeta, rB, xin, WTl[layer], ygemm, N);
    finalize_kernel<<<nb, 256, 0, stream>>>(ygemm, deg, Bv[layer], out + D * (layer + 1),
                                            layer == 0 ? xtmp : nullptr, N);
    xin = xtmp;
  }
}

// Round 6
// 762.287 us; speedup vs baseline: 8.1367x; 8.1367x over previous
//
#include <hip/hip_runtime.h>

#define D     128
#define OD    384   // 3*D output row stride
#define NK    25    // KS^2 kernels
#define KCMAX 13    // k-chunk: G chunk 166MB bf16 stays L3-resident

typedef __attribute__((ext_vector_type(8))) short bf16x8;
typedef __attribute__((ext_vector_type(4))) float f32x4;
typedef const __attribute__((address_space(1))) void gv_t;
typedef __attribute__((address_space(3))) void lv_t;

struct __align__(16) Rec {
  int src;
  unsigned int wi;   // 4 x 5-bit corner kernel indices
  unsigned int b01;  // f16 weights q0|q1
  unsigned int b23;  // f16 weights q2|q3
};

__device__ inline unsigned short f2bf(float f) {
  unsigned int u = __float_as_uint(f);
  u += 0x7fffu + ((u >> 16) & 1u);
  return (unsigned short)(u >> 16);
}
__device__ inline unsigned short f2h(float f) {
  return __builtin_bit_cast(unsigned short, (_Float16)f);
}
__device__ inline float h2f(unsigned int bits16) {
  return (float)__builtin_bit_cast(_Float16, (unsigned short)(bits16 & 0xffffu));
}

// ---------------- preprocessing: sort edges by dst ---------------------------

__global__ __launch_bounds__(256) void deg_kernel(const int* __restrict__ dstA, int E,
                                                  int* __restrict__ deg) {
  int e = blockIdx.x * 256 + threadIdx.x;
  if (e < E) atomicAdd(&deg[dstA[e]], 1);
}

__global__ __launch_bounds__(1024) void scan_kernel(const int* __restrict__ deg, int N,
                                                    int* __restrict__ base) {
  __shared__ int part[1024];
  int tid = threadIdx.x;
  int chunk = (N + 1023) / 1024;
  int s0 = min(N, tid * chunk), s1 = min(N, s0 + chunk);
  int sum = 0;
  for (int i = s0; i < s1; ++i) sum += deg[i];
  part[tid] = sum;
  __syncthreads();
  if (tid == 0) {
    int acc = 0;
    for (int i = 0; i < 1024; ++i) { int t = part[i]; part[i] = acc; acc += t; }
  }
  __syncthreads();
  int acc = part[tid];
  for (int i = s0; i < s1; ++i) { base[i] = acc; acc += deg[i]; }
}

__global__ __launch_bounds__(256) void fill_kernel(const int* __restrict__ srcA,
    const int* __restrict__ dstA, const float* __restrict__ attr, int E,
    const int* __restrict__ base, int* __restrict__ cursor, Rec* __restrict__ recs) {
  int e = blockIdx.x * 256 + threadIdx.x;
  if (e >= E) return;
  int d = dstA[e];
  int pos = base[d] + atomicAdd(&cursor[d], 1);
  float v0 = attr[2 * e] * 4.0f;
  float v1 = attr[2 * e + 1] * 4.0f;
  int i0 = min(3, max(0, (int)v0));
  int i1 = min(3, max(0, (int)v1));
  float f0 = v0 - (float)i0;
  float f1 = v1 - (float)i1;
  Rec r;
  r.src = srcA[e];
  unsigned int w00 = (unsigned int)(i0 + 5 * i1);
  r.wi = w00 | ((w00 + 1) << 5) | ((w00 + 5) << 10) | ((w00 + 6) << 15);
  r.b01 = (unsigned int)f2h((1.f - f0) * (1.f - f1)) | ((unsigned int)f2h(f0 * (1.f - f1)) << 16);
  r.b23 = (unsigned int)f2h((1.f - f0) * f1) | ((unsigned int)f2h(f0 * f1) << 16);
  recs[pos] = r;
}

// WT[n][kk] = bf16(W[kk/128][kk%128][n]), kk = k*128+i flattened, per layer
__global__ __launch_bounds__(256) void wt_kernel(const float* __restrict__ W,
                                                 unsigned short* __restrict__ WT) {
  int idx = blockIdx.x * 256 + threadIdx.x;  // over 128*3200
  if (idx >= 128 * NK * D) return;
  int n = idx / (NK * D);
  int kk = idx - n * (NK * D);
  WT[idx] = f2bf(W[(size_t)kk * D + n]);
}

// ---------------- gather: G[dst, k-chunk, :] = sum b * x[src] (bf16 in/out) --
// wave per dst, per-wave LDS f32 accumulator, 4-deep edge batching.

__global__ __launch_bounds__(256) void gather_kernel(const int* __restrict__ base,
    const int* __restrict__ deg, const Rec* __restrict__ recs,
    const unsigned short* __restrict__ Xb, unsigned short* __restrict__ Gc, int N,
    int KCc, int kc0) {
  __shared__ float lacc[4][KCMAX * D];
  int w = threadIdx.x >> 6, l = threadIdx.x & 63;
  int dst = blockIdx.x * 4 + w;
  if (dst >= N) return;
  float* A = lacc[w];
  for (int k = 0; k < KCc; ++k)
    *(float2*)(A + k * D + l * 2) = make_float2(0.f, 0.f);

  auto ACC = [&](const Rec& r, unsigned int xp) {
    float x0 = __uint_as_float(xp << 16);
    float x1 = __uint_as_float(xp & 0xffff0000u);
    float bq[4] = {h2f(r.b01), h2f(r.b01 >> 16), h2f(r.b23), h2f(r.b23 >> 16)};
#pragma unroll
    for (int q = 0; q < 4; ++q) {
      int k = (int)((r.wi >> (5 * q)) & 31u) - kc0;
      if ((unsigned)k < (unsigned)KCc) {
        float2 p = *(const float2*)(A + k * D + l * 2);
        p.x = fmaf(bq[q], x0, p.x);
        p.y = fmaf(bq[q], x1, p.y);
        *(float2*)(A + k * D + l * 2) = p;
      }
    }
  };

  int s = base[dst], e = s + deg[dst];
  int j = s;
  for (; j + 3 < e; j += 4) {
    Rec r0 = recs[j], r1 = recs[j + 1], r2 = recs[j + 2], r3 = recs[j + 3];
    unsigned int xp0 = *(const unsigned int*)(Xb + (size_t)r0.src * D + l * 2);
    unsigned int xp1 = *(const unsigned int*)(Xb + (size_t)r1.src * D + l * 2);
    unsigned int xp2 = *(const unsigned int*)(Xb + (size_t)r2.src * D + l * 2);
    unsigned int xp3 = *(const unsigned int*)(Xb + (size_t)r3.src * D + l * 2);
    ACC(r0, xp0); ACC(r1, xp1); ACC(r2, xp2); ACC(r3, xp3);
  }
  for (; j < e; ++j) {
    Rec r = recs[j];
    unsigned int xp = *(const unsigned int*)(Xb + (size_t)r.src * D + l * 2);
    ACC(r, xp);
  }

  unsigned short* gr = Gc + (size_t)dst * ((size_t)KCc * D);
  for (int k = 0; k < KCc; ++k) {
    float2 v = *(const float2*)(A + k * D + l * 2);
    unsigned int pk = (unsigned int)f2bf(v.x) | ((unsigned int)f2bf(v.y) << 16);
    *(unsigned int*)(gr + k * D + l * 2) = pk;
  }
}

// ---------------- bf16 MFMA GEMM: Y[N,128] (+)= Gc[N,KCc*128] @ W[kchunk] ----
// 128x128 tile, 4 waves, BK=64, global_load_lds w/ pre-swizzled source (T2),
// 2-phase double-buffered pipeline (stage next before compute current).

__global__ __launch_bounds__(256) void gemm_kernel(
    const unsigned short* __restrict__ G, const unsigned short* __restrict__ WT,
    float* __restrict__ Y, int N, int KCc, int kc0, int first) {
  __shared__ __attribute__((aligned(16))) char At[2][16384];
  __shared__ __attribute__((aligned(16))) char Bt[2][16384];
  const int tid = threadIdx.x;
  const int w = tid >> 6;
  const int l = tid & 63;
  const int m0 = blockIdx.x * 128;
  const size_t ldG = (size_t)KCc * 256;  // bytes per G row
  const size_t ldW = (size_t)NK * 256;   // 6400 bytes per WT row

  const int lrow = l >> 3;                       // row within 8-row group
  const int scol = ((l & 7) * 16) ^ (lrow << 4); // swizzled source column byte

  f32x4 acc[2][8];
#pragma unroll
  for (int mr = 0; mr < 2; ++mr)
#pragma unroll
    for (int nc = 0; nc < 8; ++nc) {
      if (first) {
        acc[mr][nc] = (f32x4){0.f, 0.f, 0.f, 0.f};
      } else {
        int col = nc * 16 + (l & 15);
#pragma unroll
        for (int j = 0; j < 4; ++j) {
          int row = m0 + w * 32 + mr * 16 + (l >> 4) * 4 + j;
          acc[mr][nc][j] = (row < N) ? Y[(size_t)row * D + col] : 0.f;
        }
      }
    }

  const int steps = KCc * 2;
  auto STAGE = [&](int kt, int b) {
#pragma unroll
    for (int i = 0; i < 4; ++i) {  // A: 8 G-rows per load
      int row = w * 32 + i * 8 + lrow;
      int node = m0 + row;
      if (node > N - 1) node = N - 1;
      const char* src = (const char*)G + (size_t)node * ldG + kt * 128 + scol;
      __builtin_amdgcn_global_load_lds((gv_t*)src, (lv_t*)(At[b] + (w * 4 + i) * 1024),
                                       16, 0, 0);
    }
#pragma unroll
    for (int i = 0; i < 4; ++i) {  // B from WT (n-major)
      int nr = w * 32 + i * 8 + lrow;
      const char* src = (const char*)WT + (size_t)nr * ldW + kc0 * 256 + kt * 128 + scol;
      __builtin_amdgcn_global_load_lds((gv_t*)src, (lv_t*)(Bt[b] + (w * 4 + i) * 1024),
                                       16, 0, 0);
    }
  };

  STAGE(0, 0);
  __syncthreads();  // drains vmcnt(0): buf0 ready
  for (int kt = 0; kt < steps; ++kt) {
    const int cur = kt & 1;
    if (kt + 1 < steps) STAGE(kt + 1, cur ^ 1);  // issue next tile's loads now
#pragma unroll
    for (int ks = 0; ks < 2; ++ks) {
      int kb = ks * 64 + (l >> 4) * 16;
      bf16x8 a[2], b[8];
#pragma unroll
      for (int mr = 0; mr < 2; ++mr) {
        int r = w * 32 + mr * 16 + (l & 15);
        a[mr] = *(const bf16x8*)(At[cur] + r * 128 + (kb ^ ((r & 7) << 4)));
      }
#pragma unroll
      for (int nc = 0; nc < 8; ++nc) {
        int nr = nc * 16 + (l & 15);
        b[nc] = *(const bf16x8*)(Bt[cur] + nr * 128 + (kb ^ ((nr & 7) << 4)));
      }
#pragma unroll
      for (int mr = 0; mr < 2; ++mr)
#pragma unroll
        for (int nc = 0; nc < 8; ++nc)
          acc[mr][nc] =
              __builtin_amdgcn_mfma_f32_16x16x32_bf16(a[mr], b[nc], acc[mr][nc], 0, 0, 0);
    }
    __syncthreads();  // drains vmcnt(0): next buf ready, all reads of cur done
  }

#pragma unroll
  for (int mr = 0; mr < 2; ++mr)
#pragma unroll
    for (int nc = 0; nc < 8; ++nc) {
      int col = nc * 16 + (l & 15);
#pragma unroll
      for (int j = 0; j < 4; ++j) {
        int row = m0 + w * 32 + mr * 16 + (l >> 4) * 4 + j;
        if (row < N) Y[(size_t)row * D + col] = acc[mr][nc][j];
      }
    }
}

// ---------------- per-row l2norm / finalize ---------------------------------

__global__ __launch_bounds__(256) void l2norm_x_kernel(const float* __restrict__ x,
    float* __restrict__ out, unsigned short* __restrict__ xbf, int N) {
  int g = blockIdx.x * 256 + threadIdx.x;
  int n = g >> 6, lane = g & 63;
  if (n >= N) return;
  float2 v = *(const float2*)(x + (size_t)n * D + lane * 2);
  float ss = v.x * v.x + v.y * v.y;
#pragma unroll
  for (int m = 1; m < 64; m <<= 1) ss += __shfl_xor(ss, m, 64);
  float r = 1.0f / fmaxf(sqrtf(ss), 1e-12f);
  *(float2*)(out + (size_t)n * OD + lane * 2) = make_float2(v.x * r, v.y * r);
  unsigned int pk = (unsigned int)f2bf(v.x) | ((unsigned int)f2bf(v.y) << 16);
  *(unsigned int*)(xbf + (size_t)n * D + lane * 2) = pk;
}

__global__ __launch_bounds__(256) void finalize_kernel(const float* __restrict__ y,
    const int* __restrict__ deg, const float* __restrict__ bias, float* __restrict__ out,
    unsigned short* __restrict__ xnext, int N) {
  int g = blockIdx.x * 256 + threadIdx.x;
  int n = g >> 6, lane = g & 63;
  if (n >= N) return;
  float inv = 1.0f / (float)max(deg[n], 1);
  float2 a = *(const float2*)(y + (size_t)n * D + lane * 2);
  float2 b = *(const float2*)(bias + lane * 2);
  float h0 = a.x * inv + b.x;
  float h1 = a.y * inv + b.y;
  float ss = h0 * h0 + h1 * h1;
#pragma unroll
  for (int m = 1; m < 64; m <<= 1) ss += __shfl_xor(ss, m, 64);
  float r = 1.0f / fmaxf(sqrtf(ss), 1e-12f);
  *(float2*)(out + (size_t)n * OD + lane * 2) = make_float2(h0 * r, h1 * r);
  if (xnext) {
    unsigned int pk = (unsigned int)f2bf(fmaxf(h0, 0.f)) |
                      ((unsigned int)f2bf(fmaxf(h1, 0.f)) << 16);
    *(unsigned int*)(xnext + (size_t)n * D + lane * 2) = pk;
  }
}

// ---------------- launch -----------------------------------------------------

extern "C" void kernel_launch(void* const* d_in, const int* in_sizes, int n_in,
                              void* d_out, int out_size, void* d_ws, size_t ws_size,
                              hipStream_t stream) {
  const float* x    = (const float*)d_in[0];
  const int*   ei   = (const int*)d_in[1];
  const float* attr = (const float*)d_in[2];
  const float* w0   = (const float*)d_in[3];
  const float* b0   = (const float*)d_in[4];
  const float* w1   = (const float*)d_in[5];
  const float* b1   = (const float*)d_in[6];
  float* out = (float*)d_out;

  const int N = in_sizes[0] / D;
  const int E = in_sizes[1] / 2;
  const int* srcA = ei;
  const int* dstA = ei + E;

  char* p = (char*)d_ws;
  auto carve = [&](size_t bytes) -> char* {
    char* r = p;
    p += (bytes + 255) & ~(size_t)255;
    return r;
  };
  unsigned short* xbf    = (unsigned short*)carve((size_t)N * D * 2);
  unsigned short* xtmp   = (unsigned short*)carve((size_t)N * D * 2);
  float*          ygemm  = (float*)carve((size_t)N * D * 4);
  int*            deg    = (int*)carve((size_t)N * 4);
  int*            base   = (int*)carve((size_t)N * 4);
  int*            cursor = (int*)carve((size_t)N * 4);
  Rec*            recs   = (Rec*)carve((size_t)E * sizeof(Rec));
  unsigned short* WT0    = (unsigned short*)carve((size_t)128 * NK * D * 2);
  unsigned short* WT1    = (unsigned short*)carve((size_t)128 * NK * D * 2);
  size_t used = (size_t)(p - (char*)d_ws);
  size_t remain = (ws_size > used) ? (ws_size - used) : 0;
  int KCg = (int)(remain / ((size_t)N * D * 2));  // bf16 G bytes per k
  if (KCg > KCMAX) KCg = KCMAX;
  if (KCg < 1) KCg = 1;
  unsigned short* Gc = (unsigned short*)carve((size_t)N * (size_t)KCg * D * 2);
  (void)n_in; (void)out_size;

  hipMemsetAsync(deg, 0, (size_t)N * 4, stream);
  hipMemsetAsync(cursor, 0, (size_t)N * 4, stream);

  int eb = (E + 255) / 256;
  deg_kernel<<<eb, 256, 0, stream>>>(dstA, E, deg);
  scan_kernel<<<1, 1024, 0, stream>>>(deg, N, base);
  fill_kernel<<<eb, 256, 0, stream>>>(srcA, dstA, attr, E, base, cursor, recs);
  int wtb = (128 * NK * D + 255) / 256;
  wt_kernel<<<wtb, 256, 0, stream>>>(w0, WT0);
  wt_kernel<<<wtb, 256, 0, stream>>>(w1, WT1);

  int nb = (N * 64 + 255) / 256;
  l2norm_x_kernel<<<nb, 256, 0, stream>>>(x, out, xbf, N);

  int gbg = (N + 3) / 4;              // gather: 4 waves/block, wave per dst
  int gbm = (N + 127) / 128;          // gemm: 128-row tiles
  const unsigned short* xin = xbf;
  const float* Bv[2] = {b0, b1};
  const unsigned short* WTl[2] = {WT0, WT1};
  for (int layer = 0; layer < 2; ++layer) {
    int first = 1;
    for (int kc0 = 0; kc0 < NK; kc0 += KCg) {
      int KCc = min(KCg, NK - kc0);
      gather_kernel<<<gbg, 256, 0, stream>>>(base, deg, recs, xin, Gc, N, KCc, kc0);
      gemm_kernel<<<gbm, 256, 0, stream>>>(Gc, WTl[layer], ygemm, N, KCc, kc0, first);
      first = 0;
    }
    finalize_kernel<<<nb, 256, 0, stream>>>(ygemm, deg, Bv[layer], out + D * (layer + 1),
                                            layer == 0 ? xtmp : nullptr, N);
    xin = xtmp;
  }
}